// Round 3
// baseline (136.482 us; speedup 1.0000x reference)
//
#include <hip/hip_runtime.h>
#include <hip/hip_bf16.h>
#include <math.h>

#define BATCH 16384
#define NF 26
#define ND 13
#define VOC 100000
#define KP0 448
#define KP1 416

typedef __bf16 bf16x8 __attribute__((ext_vector_type(8)));
typedef float f32x4 __attribute__((ext_vector_type(4)));
using bf16 = __hip_bfloat16;
typedef unsigned short u16;

// ---- LDS layout (bytes) ----
#define OFF_HA 0           // [64][416] bf16, swizzled, 53248 B
#define OFF_HB 53248       // [64][416] bf16, swizzled, 53248 B
#define OFF_WS 106496      // 2 x [416][32] bf16 slabs, swizzled, 26624 B each
#define WS_SZ 26624
#define OFF_PFM 159744     // 64 f32 (FM partial per row)
#define OFF_DOT 160000     // 4 x 64 f32 (final dot partials per wave)
#define LDS_TOTAL 161024

__device__ __forceinline__ void gload_lds16(const void* g, void* l) {
  __builtin_amdgcn_global_load_lds(
      (const __attribute__((address_space(1))) void*)g,
      (__attribute__((address_space(3))) void*)l, 16, 0, 0);
}

__device__ __forceinline__ u16 f2bu(float v) {
  union { __hip_bfloat16 b; u16 u; } cv;
  cv.b = __float2bfloat16(v);
  return cv.u;
}

// ---------- fused weight transpose+cast prep ----------
// wt layout: [416 n][KP k] bf16, zero-pad n>=400 and k>=K.
__global__ void prep_kernel(const float* __restrict__ w0, const float* __restrict__ w1,
                            const float* __restrict__ w2, bf16* __restrict__ wt0,
                            bf16* __restrict__ wt1, bf16* __restrict__ wt2) {
  int bid = blockIdx.x, tid = threadIdx.x;
  const float* W; bf16* Wt; int K, KP, idx;
  if (bid < 728)       { W = w0; Wt = wt0; K = 429; KP = KP0; idx = bid * 256 + tid; }
  else if (bid < 1404) { W = w1; Wt = wt1; K = 400; KP = KP1; idx = (bid - 728) * 256 + tid; }
  else                 { W = w2; Wt = wt2; K = 400; KP = KP1; idx = (bid - 1404) * 256 + tid; }
  int k = idx % KP, n = idx / KP;
  float v = (k < K && n < 400) ? W[(size_t)k * 400 + n] : 0.f;
  Wt[idx] = __float2bfloat16(v);
}

// ---------- the whole network, one block = 64 samples ----------
__global__ __launch_bounds__(256, 1) void mega_kernel(
    const int* __restrict__ xs, const float* __restrict__ xd,
    const float* __restrict__ emb1, const float* __restrict__ emb2,
    const float* __restrict__ wd, const float* __restrict__ biasp,
    const bf16* __restrict__ wt0, const bf16* __restrict__ wt1,
    const bf16* __restrict__ wt2,
    const float* __restrict__ b0, const float* __restrict__ b1,
    const float* __restrict__ b2, const float* __restrict__ fw,
    float* __restrict__ out) {
  extern __shared__ char smem[];
  const int tid = threadIdx.x;
  const int w = tid >> 6, lane = tid & 63;
  const int r = lane & 15, g = lane >> 4;
  const int brow = blockIdx.x * 64;

  // stage weight k-slab (416 rows x 32 k) into LDS buf. Linear LDS dest
  // (global_load_lds requirement), inverse-swizzled GLOBAL source so that
  // swizzled reads see logical data (rule: both-sides-or-neither).
  auto stageW = [&](int buf, const bf16* Wt, int KPb, int k) {
    char* dst = smem + OFF_WS + buf * WS_SZ;
    const char* src = (const char*)Wt;
#pragma unroll
    for (int rd = 0; rd < 7; ++rd) {
      if (rd < 6 || tid < 128) {           // 1664 chunks = 6*256 + 128
        int c = rd * 256 + tid;
        int n = c >> 2, j = c & 3;
        int kc = j ^ ((n >> 1) & 3);       // involution on 16B-chunk index
        gload_lds16(src + (size_t)n * KPb + k * 64 + kc * 16,
                    dst + (rd * 256 + w * 64) * 16);  // uniform base; HW adds lane*16
      }
    }
  };

  stageW(0, wt0, KP0 * 2, 0);  // overlap first slab with gather

  // ---- dense-feature A-frags for layer-0 k-step 13 (cols 416..447)
  bf16x8 tailA[4];
#pragma unroll
  for (int rt = 0; rt < 4; ++rt) {
    union { bf16x8 v; u16 u[8]; } t;
#pragma unroll
    for (int j = 0; j < 8; ++j) {
      int kk = g * 8 + j;
      float v = 0.f;
      if (kk < ND) v = xd[(size_t)(brow + rt * 16 + r) * ND + kk];
      t.u[j] = f2bu(v);
    }
    tailA[rt] = t.v;
  }

  // ---- gather embeddings into hA (swizzled) + FM linear/cross
  {
    float* pfm = (float*)(smem + OFF_PFM);
    for (int i = 0; i < 16; ++i) {
      int srow = w * 16 + i;
      int sg = brow + srow;
      int x4 = ((srow >> 1) & 3) << 4;
      float s_acc = 0.f, sq_acc = 0.f, lin = 0.f;
#pragma unroll
      for (int it = 0; it < 7; ++it) {
        int f = it * 4 + g;
        if (f < NF) {
          int idx = xs[sg * NF + f];
          float v = emb2[((size_t)f * VOC + idx) * 16 + r];
          int byte = srow * 832 + (((f * 16 + r) * 2) ^ x4);
          *(u16*)(smem + OFF_HA + byte) = f2bu(v);
          s_acc += v;
          sq_acc += v * v;
          if (r == 0) lin += emb1[(size_t)f * VOC + idx];
        }
      }
      float st = s_acc;
      st += __shfl_xor(st, 16);
      st += __shfl_xor(st, 32);
      float r0v = st * st, r1v = sq_acc, r2v = lin;
#pragma unroll
      for (int off = 1; off < 64; off <<= 1) {
        r0v += __shfl_xor(r0v, off);
        r1v += __shfl_xor(r1v, off);
        r2v += __shfl_xor(r2v, off);
      }
      if (lane == 0) pfm[srow] = r2v + 0.5f * (0.25f * r0v - r1v);
    }
  }
  __syncthreads();

  int curbuf = 0;
  const int ntc = (w < 2) ? 7 : 6;                 // col tiles per wave (7/7/6/6)
  const int nt0 = (w < 2) ? w * 7 : 14 + (w - 2) * 6;

  auto ldA = [&](int actOff, int k, int rt) -> bf16x8 {
    int row = rt * 16 + r;
    int byte = row * 832 + k * 64 + ((g ^ ((row >> 1) & 3)) << 4);
    return *(const bf16x8*)(smem + actOff + byte);
  };
  auto ldB = [&](int nt) -> bf16x8 {
    int n = nt * 16 + r;
    int byte = n * 64 + ((g ^ ((n >> 1) & 3)) << 4);
    return *(const bf16x8*)(smem + OFF_WS + curbuf * WS_SZ + byte);
  };

  // ---- mid layer: relu(A@W+b) -> bf16 swizzled into outOff
  auto runMid = [&](int inOff, int outOff, bool tail, int NK,
                    const bf16* WtCur, int KPb, const bf16* WtNext, int KPbN,
                    const float* bias) {
    f32x4 acc[4][7];
#pragma unroll
    for (int a = 0; a < 4; ++a)
#pragma unroll
      for (int b = 0; b < 7; ++b) acc[a][b] = (f32x4){0.f, 0.f, 0.f, 0.f};
    for (int k = 0; k < NK; ++k) {
      if (k + 1 < NK) stageW(curbuf ^ 1, WtCur, KPb, k + 1);
      else stageW(curbuf ^ 1, WtNext, KPbN, 0);   // prefetch next layer k0
      bf16x8 a[4];
#pragma unroll
      for (int rt = 0; rt < 4; ++rt)
        a[rt] = (tail && k == NK - 1) ? tailA[rt] : ldA(inOff, k, rt);
#pragma unroll
      for (int nt = 0; nt < 7; ++nt)
        if (nt < ntc) {
          bf16x8 bfr = ldB(nt0 + nt);
#pragma unroll
          for (int rt = 0; rt < 4; ++rt)
            acc[rt][nt] = __builtin_amdgcn_mfma_f32_16x16x32_bf16(a[rt], bfr, acc[rt][nt], 0, 0, 0);
        }
      __syncthreads();
      curbuf ^= 1;
    }
#pragma unroll
    for (int nt = 0; nt < 7; ++nt)
      if (nt < ntc) {
        int col = (nt0 + nt) * 16 + r;
        bool live = col < 400;
        float bv = live ? bias[col] : 0.f;
#pragma unroll
        for (int rt = 0; rt < 4; ++rt)
#pragma unroll
          for (int q = 0; q < 4; ++q) {
            float v = live ? fmaxf(acc[rt][nt][q] + bv, 0.f) : 0.f;
            int row = rt * 16 + g * 4 + q;
            int byte = row * 832 + ((col * 2) ^ (((row >> 1) & 3) << 4));
            *(u16*)(smem + outOff + byte) = f2bu(v);
          }
      }
    __syncthreads();
  };

  runMid(OFF_HA, OFF_HB, true, 14, wt0, KP0 * 2, wt1, KP1 * 2, b0);
  runMid(OFF_HB, OFF_HA, false, 13, wt1, KP1 * 2, wt2, KP1 * 2, b1);

  // ---- final layer: relu(A@W2+b2) . fw  -> dot partials -> sigmoid
  {
    f32x4 acc[4][7];
#pragma unroll
    for (int a = 0; a < 4; ++a)
#pragma unroll
      for (int b = 0; b < 7; ++b) acc[a][b] = (f32x4){0.f, 0.f, 0.f, 0.f};
    for (int k = 0; k < 13; ++k) {
      if (k + 1 < 13) stageW(curbuf ^ 1, wt2, KP1 * 2, k + 1);
      bf16x8 a[4];
#pragma unroll
      for (int rt = 0; rt < 4; ++rt) a[rt] = ldA(OFF_HA, k, rt);
#pragma unroll
      for (int nt = 0; nt < 7; ++nt)
        if (nt < ntc) {
          bf16x8 bfr = ldB(nt0 + nt);
#pragma unroll
          for (int rt = 0; rt < 4; ++rt)
            acc[rt][nt] = __builtin_amdgcn_mfma_f32_16x16x32_bf16(a[rt], bfr, acc[rt][nt], 0, 0, 0);
        }
      __syncthreads();
      curbuf ^= 1;
    }
    float pr[4][4] = {{0.f}};
#pragma unroll
    for (int nt = 0; nt < 7; ++nt)
      if (nt < ntc) {
        int col = (nt0 + nt) * 16 + r;
        if (col < 400) {
          float bv = b2[col], fv = fw[col];
#pragma unroll
          for (int rt = 0; rt < 4; ++rt)
#pragma unroll
            for (int q = 0; q < 4; ++q)
              pr[rt][q] += fmaxf(acc[rt][nt][q] + bv, 0.f) * fv;
        }
      }
#pragma unroll
    for (int rt = 0; rt < 4; ++rt)
#pragma unroll
      for (int q = 0; q < 4; ++q) {
        pr[rt][q] += __shfl_xor(pr[rt][q], 1);
        pr[rt][q] += __shfl_xor(pr[rt][q], 2);
        pr[rt][q] += __shfl_xor(pr[rt][q], 4);
        pr[rt][q] += __shfl_xor(pr[rt][q], 8);
      }
    float* dr = (float*)(smem + OFF_DOT);
    if (r < 4) {
#pragma unroll
      for (int rt = 0; rt < 4; ++rt) {
        float v = (r == 0) ? pr[rt][0] : (r == 1) ? pr[rt][1]
                : (r == 2) ? pr[rt][2] : pr[rt][3];
        dr[w * 64 + rt * 16 + g * 4 + r] = v;
      }
    }
    __syncthreads();
    if (tid < 64) {
      const float* pfm = (const float*)(smem + OFF_PFM);
      float x = pfm[tid] + dr[tid] + dr[64 + tid] + dr[128 + tid] + dr[192 + tid];
#pragma unroll
      for (int d = 0; d < ND; ++d)
        x += xd[(size_t)(brow + tid) * ND + d] * wd[d];
      x += biasp[0];
      out[brow + tid] = 1.f / (1.f + expf(-x));
    }
  }
}

extern "C" void kernel_launch(void* const* d_in, const int* in_sizes, int n_in,
                              void* d_out, int out_size, void* d_ws, size_t ws_size,
                              hipStream_t stream) {
  const int* xs = (const int*)d_in[0];
  const float* xd = (const float*)d_in[1];
  const float* emb1 = (const float*)d_in[2];
  const float* emb2 = (const float*)d_in[3];
  const float* wd = (const float*)d_in[4];
  const float* bias = (const float*)d_in[5];
  const float* w0 = (const float*)d_in[6];
  const float* b0 = (const float*)d_in[7];
  const float* w1 = (const float*)d_in[8];
  const float* b1 = (const float*)d_in[9];
  const float* w2 = (const float*)d_in[10];
  const float* b2 = (const float*)d_in[11];
  const float* fw = (const float*)d_in[12];
  float* out = (float*)d_out;

  char* ws = (char*)d_ws;
  bf16* wt0 = (bf16*)(ws + 0);        // 416*448*2 = 372736
  bf16* wt1 = (bf16*)(ws + 372736);   // 416*416*2 = 346112
  bf16* wt2 = (bf16*)(ws + 718848);   // 346112 -> end 1064960

  hipFuncSetAttribute((const void*)mega_kernel,
                      hipFuncAttributeMaxDynamicSharedMemorySize, LDS_TOTAL);

  prep_kernel<<<2080, 256, 0, stream>>>(w0, w1, w2, wt0, wt1, wt2);
  mega_kernel<<<256, 256, LDS_TOTAL, stream>>>(xs, xd, emb1, emb2, wd, bias,
                                               wt0, wt1, wt2, b0, b1, b2, fw, out);
}

// Round 4
// 80.014 us; speedup vs baseline: 1.7057x; 1.7057x over previous
//
#include <hip/hip_runtime.h>
#include <hip/hip_bf16.h>
#include <math.h>

#define BATCH 16384
#define NF 26
#define ND 13
#define VOC 100000
#define KP0 448
#define KP1 416

typedef __bf16 bf16x8 __attribute__((ext_vector_type(8)));
typedef float f32x4 __attribute__((ext_vector_type(4)));
using bf16 = __hip_bfloat16;

__device__ __forceinline__ void gload_lds16(const void* g, void* l) {
  __builtin_amdgcn_global_load_lds(
      (const __attribute__((address_space(1))) void*)g,
      (__attribute__((address_space(3))) void*)l, 16, 0, 0);
}

// ---------- fused weight transpose+cast: Wt[n][k], 416 rows, zero-pad ----------
__global__ void prep_kernel(const float* __restrict__ w0, const float* __restrict__ w1,
                            const float* __restrict__ w2, bf16* __restrict__ wt0,
                            bf16* __restrict__ wt1, bf16* __restrict__ wt2) {
  int bid = blockIdx.x, tid = threadIdx.x;
  const float* W; bf16* Wt; int K, KP, idx;
  if (bid < 728)       { W = w0; Wt = wt0; K = 429; KP = KP0; idx = bid * 256 + tid; }
  else if (bid < 1404) { W = w1; Wt = wt1; K = 400; KP = KP1; idx = (bid - 728) * 256 + tid; }
  else                 { W = w2; Wt = wt2; K = 400; KP = KP1; idx = (bid - 1404) * 256 + tid; }
  int k = idx % KP, n = idx / KP;
  float v = (k < K && n < 400) ? W[(size_t)k * 400 + n] : 0.f;
  Wt[idx] = __float2bfloat16(v);
}

// ---------- gather + FM terms. One wave per sample. ----------
__global__ __launch_bounds__(256) void gather_fm_kernel(
    const int* __restrict__ xs, const float* __restrict__ xd,
    const float* __restrict__ emb1, const float* __restrict__ emb2,
    const float* __restrict__ wd, const float* __restrict__ bias,
    bf16* __restrict__ h0, float* __restrict__ partial) {
  int gid = blockIdx.x * blockDim.x + threadIdx.x;
  int b = gid >> 6;
  int lane = threadIdx.x & 63;
  int fsub = lane >> 4;      // 0..3
  int e = lane & 15;         // 0..15
  float s_acc = 0.f, sq_acc = 0.f, lin = 0.f;
#pragma unroll
  for (int it = 0; it < 7; ++it) {
    int f = it * 4 + fsub;
    if (f < NF) {
      int idx = xs[b * NF + f];
      float v = emb2[((size_t)(f * VOC + idx)) * 16 + e];
      h0[(size_t)b * KP0 + f * 16 + e] = __float2bfloat16(v);
      s_acc += v;
      sq_acc += v * v;
      if (e == 0) lin += emb1[(size_t)f * VOC + idx];
    }
  }
  if (lane < 32) {
    float v = 0.f;
    if (lane < ND) { v = xd[b * ND + lane]; lin += v * wd[lane]; }
    h0[(size_t)b * KP0 + 416 + lane] = __float2bfloat16(v);
  }
  float s_tot = s_acc;
  s_tot += __shfl_xor(s_tot, 16);
  s_tot += __shfl_xor(s_tot, 32);
  float r0 = s_tot * s_tot;   // each e duplicated 4x -> /4 later
  float r1 = sq_acc;
  float r2 = lin;
#pragma unroll
  for (int off = 1; off < 64; off <<= 1) {
    r0 += __shfl_xor(r0, off);
    r1 += __shfl_xor(r1, off);
    r2 += __shfl_xor(r2, off);
  }
  if (lane == 0) {
    float cross = 0.5f * (r0 * 0.25f - r1);
    partial[b] = bias[0] + r2 + cross;
  }
}

// ---------- MFMA GEMM. Block: 64 rows x 208 cols (ch). 4 waves x 16 rows.
// B k-slab in LDS (208x32 bf16, XOR-swizzled), double-buffered, staged via
// global_load_lds from inverse-swizzled source addresses (both-sides rule).
// grid 512 -> 2 blocks/CU, 2 waves/SIMD.
template <int KP, bool FINAL>
__global__ __launch_bounds__(256) void mlp3_kernel(
    const bf16* __restrict__ A, const bf16* __restrict__ Wt,
    const float* __restrict__ bias, bf16* __restrict__ outH,
    const float* __restrict__ fw, float* __restrict__ dotb) {
  constexpr int NK = KP / 32;
  __shared__ __align__(16) bf16 slab[2][208 * 32];
  const int bid = blockIdx.x;
  const int ch = bid & 1;
  const int tid = threadIdx.x, w = tid >> 6, lane = tid & 63;
  const int r = lane & 15, g = lane >> 4;
  const int row0 = (bid >> 1) * 64 + w * 16;
  const int ncol0 = ch * 208;
  const char* wbase = (const char*)(Wt + (size_t)ncol0 * KP);

  // stage k-slab into slab[buf]: 832 x 16B chunks, linear LDS dest,
  // inverse-swizzled global source (kc = j ^ ((n>>1)&3), an involution).
  auto stage = [&](int buf, int k) {
#pragma unroll
    for (int rd = 0; rd < 4; ++rd) {
      int c = rd * 256 + tid;
      if (c < 832) {
        int n = c >> 2, j = c & 3;
        int kc = j ^ ((n >> 1) & 3);
        gload_lds16(wbase + (size_t)n * (KP * 2) + k * 64 + kc * 16,
                    (char*)&slab[buf][0] + (rd * 256 + w * 64) * 16);
      }
    }
  };

  const char* Ab = (const char*)(A + (size_t)(row0 + r) * KP) + g * 16;
  bf16x8 aNext = *(const bf16x8*)(Ab);   // issue A before stage: counted wait
  stage(0, 0);
  __syncthreads();

  f32x4 acc[13];
#pragma unroll
  for (int nt = 0; nt < 13; ++nt) acc[nt] = (f32x4){0.f, 0.f, 0.f, 0.f};

  const int chunkoff = ((g ^ ((r >> 1) & 3)) << 4);
  int cur = 0;
  for (int k = 0; k < NK; ++k) {
    bf16x8 aCur = aNext;
    if (k + 1 < NK) {
      aNext = *(const bf16x8*)(Ab + (k + 1) * 64);
      stage(cur ^ 1, k + 1);
    }
    const char* sb = (const char*)&slab[cur][0] + r * 64 + chunkoff;
#pragma unroll
    for (int nt = 0; nt < 13; ++nt) {
      bf16x8 b = *(const bf16x8*)(sb + nt * 1024);
      acc[nt] = __builtin_amdgcn_mfma_f32_16x16x32_bf16(aCur, b, acc[nt], 0, 0, 0);
    }
    __syncthreads();
    cur ^= 1;
  }

  if (!FINAL) {
#pragma unroll
    for (int nt = 0; nt < 13; ++nt) {
      int col = ncol0 + nt * 16 + r;
      bool live = (col < 400);
      float bv = live ? bias[col] : 0.f;
#pragma unroll
      for (int q = 0; q < 4; ++q) {
        float v = live ? fmaxf(acc[nt][q] + bv, 0.f) : 0.f;
        outH[(size_t)(row0 + g * 4 + q) * KP1 + col] = __float2bfloat16(v);
      }
    }
  } else {
    float pr[4] = {0.f, 0.f, 0.f, 0.f};
#pragma unroll
    for (int nt = 0; nt < 13; ++nt) {
      int col = ncol0 + nt * 16 + r;
      if (col < 400) {
        float bv = bias[col], fv = fw[col];
#pragma unroll
        for (int q = 0; q < 4; ++q)
          pr[q] += fmaxf(acc[nt][q] + bv, 0.f) * fv;
      }
    }
#pragma unroll
    for (int q = 0; q < 4; ++q) {
      pr[q] += __shfl_xor(pr[q], 1);
      pr[q] += __shfl_xor(pr[q], 2);
      pr[q] += __shfl_xor(pr[q], 4);
      pr[q] += __shfl_xor(pr[q], 8);
    }
    if (r < 4) {
      float v = (r == 0) ? pr[0] : (r == 1) ? pr[1] : (r == 2) ? pr[2] : pr[3];
      dotb[(size_t)ch * BATCH + row0 + g * 4 + r] = v;
    }
  }
}

// ---------- combine partials + sigmoid ----------
__global__ void finish_kernel(const float* __restrict__ partial,
                              const float* __restrict__ dotb,
                              float* __restrict__ out) {
  int i = blockIdx.x * 256 + threadIdx.x;
  if (i < BATCH) {
    float x = partial[i] + dotb[i] + dotb[i + BATCH];
    out[i] = 1.f / (1.f + expf(-x));
  }
}

extern "C" void kernel_launch(void* const* d_in, const int* in_sizes, int n_in,
                              void* d_out, int out_size, void* d_ws, size_t ws_size,
                              hipStream_t stream) {
  const int* xs = (const int*)d_in[0];
  const float* xd = (const float*)d_in[1];
  const float* emb1 = (const float*)d_in[2];
  const float* emb2 = (const float*)d_in[3];
  const float* wd = (const float*)d_in[4];
  const float* bias = (const float*)d_in[5];
  const float* w0 = (const float*)d_in[6];
  const float* b0 = (const float*)d_in[7];
  const float* w1 = (const float*)d_in[8];
  const float* b1 = (const float*)d_in[9];
  const float* w2 = (const float*)d_in[10];
  const float* b2 = (const float*)d_in[11];
  const float* fw = (const float*)d_in[12];
  float* out = (float*)d_out;

  char* ws = (char*)d_ws;
  float* partial = (float*)(ws + 0);        //  65536 B
  float* dotb    = (float*)(ws + 65536);    // 131072 B
  bf16* wt0 = (bf16*)(ws + 196608);         // 416*448*2 = 372736
  bf16* wt1 = (bf16*)(ws + 569344);         // 416*416*2 = 346112
  bf16* wt2 = (bf16*)(ws + 915456);         // 346112
  bf16* h0  = (bf16*)(ws + 1261568);        // 16384*448*2 = 14680064
  bf16* h1  = (bf16*)(ws + 15941632);       // 16384*416*2 = 13631488
  bf16* h2  = h0;                           // h0 dead after layer 0

  prep_kernel<<<2080, 256, 0, stream>>>(w0, w1, w2, wt0, wt1, wt2);
  gather_fm_kernel<<<BATCH / 4, 256, 0, stream>>>(xs, xd, emb1, emb2, wd, bias, h0, partial);

  mlp3_kernel<KP0, false><<<512, 256, 0, stream>>>(h0, wt0, b0, h1, nullptr, nullptr);
  mlp3_kernel<KP1, false><<<512, 256, 0, stream>>>(h1, wt1, b1, h2, nullptr, nullptr);
  mlp3_kernel<KP1, true><<<512, 256, 0, stream>>>(h2, wt2, b2, nullptr, fw, dotb);

  finish_kernel<<<BATCH / 256, 256, 0, stream>>>(partial, dotb, out);
}